// Round 6
// baseline (635.519 us; speedup 1.0000x reference)
//
#include <hip/hip_runtime.h>

typedef unsigned short u16;
typedef unsigned int u32;

#define SEQ 96
#define DM 512
#define NBATCH 512
#define NFREQ 49
#define CUT 16
#define MROWS (NBATCH * SEQ)  // 49152

typedef __attribute__((ext_vector_type(8))) short bf16x8;
typedef __attribute__((ext_vector_type(4))) float f32x4;

// ---------- bf16 helpers (manual, RNE) ----------
__device__ __forceinline__ u16 f2bf(float f) {
  u32 u = __float_as_uint(f);
  u32 r = (u + 0x7fffu + ((u >> 16) & 1u)) >> 16;
  return (u16)r;
}

// async global->LDS, 16B per lane; lds base wave-uniform, lands at base+lane*16.
__device__ __forceinline__ void g2l16(const void* g, void* l) {
  __builtin_amdgcn_global_load_lds(
      (const __attribute__((address_space(1))) void*)g,
      (__attribute__((address_space(3))) void*)l, 16, 0, 0);
}

// ---------- K1: build spectral filter matrices Fl/Fh [96x96] bf16 ----------
__global__ void build_filters_k(const float* __restrict__ w,
                                u16* __restrict__ FlB, u16* __restrict__ FhB) {
  int idx = blockIdx.x * 256 + threadIdx.x;
  if (idx >= SEQ * SEQ) return;
  int s = idx / SEQ, t = idx % SEQ;
  int d = s - t;
  const float scale = 1.0f / (float)SEQ;
  const float w0 = 6.283185307179586f / (float)SEQ;
  float cl = 0.f, ch = 0.f;
  for (int k = 0; k < NFREQ; k++) {
    int m = (k * d) % SEQ;
    if (m < 0) m += SEQ;
    float c = (k == 0 || k == SEQ / 2) ? 1.0f : 2.0f;
    float v = c * w[k] * cosf(w0 * (float)m) * scale;
    if (k < CUT) cl += v; else ch += v;
  }
  FlB[idx] = f2bf(cl);
  FhB[idx] = f2bf(ch);
}

// ---------- K2: A1 = Wl@Wg1, A2 = Wh@Wg2 (fp32, small) ----------
__global__ void __launch_bounds__(256) smallgemm_k(
    const float* __restrict__ Wl, const float* __restrict__ Wh,
    const float* __restrict__ Wg, float* __restrict__ A1f,
    float* __restrict__ A2f) {
  const float* A = blockIdx.z ? Wh : Wl;
  const float* B = Wg + (size_t)blockIdx.z * 512 * 512;
  float* O = blockIdx.z ? A2f : A1f;
  __shared__ float As[64][16];
  __shared__ float Bs[16][64];
  int i0 = blockIdx.x * 64, j0 = blockIdx.y * 64;
  int tid = threadIdx.x;
  int tx = tid & 15, ty = tid >> 4;
  float acc[4][4] = {};
  for (int k0 = 0; k0 < 512; k0 += 16) {
    __syncthreads();
    #pragma unroll
    for (int v = 0; v < 4; v++) {
      int c = v * 256 + tid;
      As[c >> 4][c & 15] = A[(size_t)(i0 + (c >> 4)) * 512 + k0 + (c & 15)];
      Bs[c >> 6][c & 63] = B[(size_t)(k0 + (c >> 6)) * 512 + j0 + (c & 63)];
    }
    __syncthreads();
    #pragma unroll
    for (int kk = 0; kk < 16; kk++) {
      float av[4], bv[4];
      #pragma unroll
      for (int ii = 0; ii < 4; ii++) av[ii] = As[ty * 4 + ii][kk];
      #pragma unroll
      for (int jj = 0; jj < 4; jj++) bv[jj] = Bs[kk][tx * 4 + jj];
      #pragma unroll
      for (int ii = 0; ii < 4; ii++)
        #pragma unroll
        for (int jj = 0; jj < 4; jj++)
          acc[ii][jj] = fmaf(av[ii], bv[jj], acc[ii][jj]);
    }
  }
  #pragma unroll
  for (int ii = 0; ii < 4; ii++)
    #pragma unroll
    for (int jj = 0; jj < 4; jj++)
      O[(size_t)(i0 + ty * 4 + ii) * 512 + j0 + tx * 4 + jj] = acc[ii][jj];
}

// ---------- K3: cb[j] = bg[j] + bl@Wg1[:,j] + bh@Wg2[:,j] ----------
__global__ void __launch_bounds__(256) cbias_k(
    const float* __restrict__ bl, const float* __restrict__ bh,
    const float* __restrict__ Wg, const float* __restrict__ bg,
    float* __restrict__ cb) {
  int j = blockIdx.x * 256 + threadIdx.x;
  float acc = bg[j];
  for (int k = 0; k < 512; k++) acc = fmaf(bl[k], Wg[(size_t)k * 512 + j], acc);
  for (int k = 0; k < 512; k++) acc = fmaf(bh[k], Wg[(size_t)(512 + k) * 512 + j], acc);
  cb[j] = acc;
}

// ---------- K4: transpose fp32 [K,N] weight -> bf16 [N,K] ----------
__global__ void __launch_bounds__(256) transpose_w_k(
    const float* __restrict__ W, u16* __restrict__ Wt, int K, int N) {
  __shared__ float t[32][33];
  int k0 = blockIdx.x * 32, n0 = blockIdx.y * 32;
  int tx = threadIdx.x & 31, ty = threadIdx.x >> 5;
  #pragma unroll
  for (int r = 0; r < 32; r += 8)
    t[ty + r][tx] = W[(size_t)(k0 + ty + r) * N + n0 + tx];
  __syncthreads();
  #pragma unroll
  for (int r = 0; r < 32; r += 8)
    Wt[(size_t)(n0 + ty + r) * K + k0 + tx] = f2bf(t[tx][ty + r]);
}

// ---------- K5: mega GEMM: [u|v|p1|p2] = X @ W4, epilogue transposes to
// [b][e][s] bf16. X fp32 (converted in staging). W4t [2048][512] bf16.
// 256x128 tile, BK=32, 4 waves 2x2 each 128x64.
__global__ void __launch_bounds__(256, 2) mega_k(
    const float* __restrict__ x, const u16* __restrict__ W4t,
    u16* __restrict__ uT, u16* __restrict__ vT,
    u16* __restrict__ p1T, u16* __restrict__ p2T) {
  __shared__ __align__(16) u16 As[256 * 32];  // 16 KB
  __shared__ __align__(16) u16 Bs[128 * 32];  // 8 KB
  const int n0 = blockIdx.x * 128;   // n fast-varying -> A-tile L2 reuse
  const int m0 = blockIdx.y * 256;
  const int tid = threadIdx.x;
  const int lane = tid & 63;
  const int w = tid >> 6;
  const int wm = w & 1, wn = w >> 1;
  const int l15 = lane & 15;
  const int lq = lane >> 4;

  f32x4 acc[8][4] = {};

  for (int kt = 0; kt < 512; kt += 32) {
    // A: fp32 load + convert + ds_write (256 rows x 32 k)
    #pragma unroll
    for (int it = 0; it < 4; it++) {
      int u = it * 256 + tid;           // 8-float unit
      int row = u >> 2, k8 = (u & 3) << 3;
      const float* src = x + (size_t)(m0 + row) * 512 + kt + k8;
      float4 f0 = *(const float4*)src;
      float4 f1 = *(const float4*)(src + 4);
      uint4 o;
      o.x = (u32)f2bf(f0.x) | ((u32)f2bf(f0.y) << 16);
      o.y = (u32)f2bf(f0.z) | ((u32)f2bf(f0.w) << 16);
      o.z = (u32)f2bf(f1.x) | ((u32)f2bf(f1.y) << 16);
      o.w = (u32)f2bf(f1.z) | ((u32)f2bf(f1.w) << 16);
      *(uint4*)&As[row * 32 + k8] = o;
    }
    // B: async direct-to-LDS: 128 rows x 32 k = 512 chunks (2 iters x 256).
    // chunk c -> LDS byte 16c == row-major Bs[row*32 + off] (verified r3 pattern)
    #pragma unroll
    for (int r = 0; r < 2; r++) {
      int c = r * 256 + tid;
      int row = c >> 2, off = (c & 3) << 3;
      u32 lo = (u32)((r * 256 + w * 64) << 4);
      g2l16(W4t + (size_t)(n0 + row) * 512 + kt + off, (char*)Bs + lo);
    }
    __syncthreads();
    bf16x8 af[8], bf[4];
    #pragma unroll
    for (int i = 0; i < 8; i++)
      af[i] = *(const bf16x8*)&As[(wm * 128 + i * 16 + l15) * 32 + lq * 8];
    #pragma unroll
    for (int j = 0; j < 4; j++)
      bf[j] = *(const bf16x8*)&Bs[(wn * 64 + j * 16 + l15) * 32 + lq * 8];
    #pragma unroll
    for (int i = 0; i < 8; i++)
      #pragma unroll
      for (int j = 0; j < 4; j++)
        acc[i][j] = __builtin_amdgcn_mfma_f32_16x16x32_bf16(af[i], bf[j], acc[i][j], 0, 0, 0);
    __syncthreads();
  }

  u16* dst = (n0 < 512) ? uT : (n0 < 1024) ? vT : (n0 < 1536) ? p1T : p2T;
  const int e0 = (n0 & 511) + wn * 64;
  #pragma unroll
  for (int j = 0; j < 4; j++) {
    int e = e0 + j * 16 + l15;
    #pragma unroll
    for (int i = 0; i < 8; i++) {
      int m = m0 + wm * 128 + i * 16 + lq * 4;
      int b = m / 96, s = m - b * 96;   // s%4==0, never crosses batch
      ushort4 st;
      st.x = f2bf(acc[i][j][0]);
      st.y = f2bf(acc[i][j][1]);
      st.z = f2bf(acc[i][j][2]);
      st.w = f2bf(acc[i][j][3]);
      *(ushort4*)&dst[((size_t)b * 512 + e) * SEQ + s] = st;
    }
  }
}

// ---------- K6: tail: yl=Fl@u+bl, yh=Fh@v+bh, g=sigmoid(Fl@p1+Fh@p2+cb),
// y = x + g*yl + (1-g)*yh  -> write fp32 into out (pre-LN). Per-batch block.
__global__ void __launch_bounds__(256) tail_k(
    const u16* __restrict__ uT, const u16* __restrict__ vT,
    const u16* __restrict__ p1T, const u16* __restrict__ p2T,
    const u16* __restrict__ FlB, const float* __restrict__ bl,
    const float* __restrict__ bh, const float* __restrict__ cb,
    const float* __restrict__ x, float* __restrict__ y) {
  __shared__ __align__(16) u16 F[2 * SEQ * SEQ];  // 36,864 B
  const int tid = threadIdx.x;
  const int lane = tid & 63, w = tid >> 6;
  const int l15 = lane & 15, lq = lane >> 4;
  const int b = blockIdx.x;

  // stage Fl;Fh (contiguous in ws): 2304 x 16B chunks
  #pragma unroll
  for (int it = 0; it < 9; it++) {
    int c = it * 256 + tid;
    g2l16(FlB + c * 8, (char*)F + ((it * 256 + w * 64) << 4));
  }
  __syncthreads();

  for (int ch = 0; ch < 8; ch++) {
    int d0c = ch * 64 + w * 16;  // this wave's 16 d-columns
    const u16* bu = uT + ((size_t)b * 512 + d0c) * SEQ;
    const u16* bv = vT + ((size_t)b * 512 + d0c) * SEQ;
    const u16* bp1 = p1T + ((size_t)b * 512 + d0c) * SEQ;
    const u16* bp2 = p2T + ((size_t)b * 512 + d0c) * SEQ;
    f32x4 accl[6] = {}, acch[6] = {}, accg[6] = {};
    #pragma unroll
    for (int ks = 0; ks < 3; ks++) {
      int kt = ks * 32;
      int boff = l15 * SEQ + kt + lq * 8;
      bf16x8 BU = *(const bf16x8*)&bu[boff];
      bf16x8 BV = *(const bf16x8*)&bv[boff];
      bf16x8 BP1 = *(const bf16x8*)&bp1[boff];
      bf16x8 BP2 = *(const bf16x8*)&bp2[boff];
      #pragma unroll
      for (int i = 0; i < 6; i++) {
        int aoff = (i * 16 + l15) * SEQ + kt + lq * 8;
        bf16x8 afl = *(const bf16x8*)&F[aoff];
        bf16x8 afh = *(const bf16x8*)&F[SEQ * SEQ + aoff];
        accl[i] = __builtin_amdgcn_mfma_f32_16x16x32_bf16(afl, BU, accl[i], 0, 0, 0);
        acch[i] = __builtin_amdgcn_mfma_f32_16x16x32_bf16(afh, BV, acch[i], 0, 0, 0);
        accg[i] = __builtin_amdgcn_mfma_f32_16x16x32_bf16(afl, BP1, accg[i], 0, 0, 0);
        accg[i] = __builtin_amdgcn_mfma_f32_16x16x32_bf16(afh, BP2, accg[i], 0, 0, 0);
      }
    }
    int d = d0c + l15;
    float blv = bl[d], bhv = bh[d], cbv = cb[d];
    #pragma unroll
    for (int i = 0; i < 6; i++)
      #pragma unroll
      for (int r = 0; r < 4; r++) {
        int s = i * 16 + lq * 4 + r;
        size_t idx = ((size_t)b * SEQ + s) * 512 + d;
        float ylv = accl[i][r] + blv;
        float yhv = acch[i][r] + bhv;
        float gv = 1.0f / (1.0f + __expf(-(accg[i][r] + cbv)));
        y[idx] = x[idx] + gv * ylv + (1.0f - gv) * yhv;
      }
  }
}

// ---------- K7: in-place LayerNorm over rows of y (=out) ----------
__global__ void __launch_bounds__(256) ln_inplace_k(
    float* __restrict__ y, const float* __restrict__ gamma,
    const float* __restrict__ beta) {
  __shared__ float red[8];
  size_t base = (size_t)blockIdx.x * 512;
  float vv[2];
  float sum = 0.f, sumsq = 0.f;
  #pragma unroll
  for (int j = 0; j < 2; j++) {
    int e = threadIdx.x + j * 256;
    float v = y[base + e];
    vv[j] = v;
    sum += v;
    sumsq += v * v;
  }
  #pragma unroll
  for (int off = 32; off; off >>= 1) {
    sum += __shfl_down(sum, off);
    sumsq += __shfl_down(sumsq, off);
  }
  int wid = threadIdx.x >> 6;
  if ((threadIdx.x & 63) == 0) {
    red[wid] = sum;
    red[4 + wid] = sumsq;
  }
  __syncthreads();
  sum = red[0] + red[1] + red[2] + red[3];
  sumsq = red[4] + red[5] + red[6] + red[7];
  float mu = sum * (1.f / 512.f);
  float var = sumsq * (1.f / 512.f) - mu * mu;
  float inv = rsqrtf(var + 1e-5f);
  #pragma unroll
  for (int j = 0; j < 2; j++) {
    int e = threadIdx.x + j * 256;
    y[base + e] = (vv[j] - mu) * inv * gamma[e] + beta[e];
  }
}

extern "C" void kernel_launch(void* const* d_in, const int* in_sizes, int n_in,
                              void* d_out, int out_size, void* d_ws, size_t ws_size,
                              hipStream_t stream) {
  const float* x     = (const float*)d_in[0];
  const float* fw    = (const float*)d_in[1];
  const float* Wl    = (const float*)d_in[2];
  const float* bl    = (const float*)d_in[3];
  const float* Wh    = (const float*)d_in[4];
  const float* bh    = (const float*)d_in[5];
  const float* Wg    = (const float*)d_in[6];
  const float* bg    = (const float*)d_in[7];
  const float* gamma = (const float*)d_in[8];
  const float* beta  = (const float*)d_in[9];
  float* out = (float*)d_out;

  char* ws = (char*)d_ws;
  u16* FlB = (u16*)ws;                              // [96*96] bf16, FhB contiguous
  u16* FhB = FlB + SEQ * SEQ;
  float* cb  = (float*)(ws + 40960);                // 512 f32
  float* A1f = (float*)(ws + 1 * 1024 * 1024);      // 512x512 fp32
  float* A2f = (float*)(ws + 2 * 1024 * 1024);
  u16* W4t = (u16*)(ws + 4 * 1024 * 1024);          // [2048][512] bf16
  size_t tsz = (size_t)MROWS * 512;                 // 25,165,824 elems
  u16* uT  = (u16*)(ws + 8 * 1024 * 1024);          // [512][512][96] bf16 each
  u16* vT  = uT + tsz;
  u16* p1T = vT + tsz;
  u16* p2T = p1T + tsz;

  build_filters_k<<<dim3(36), dim3(256), 0, stream>>>(fw, FlB, FhB);
  smallgemm_k<<<dim3(8, 8, 2), dim3(256), 0, stream>>>(Wl, Wh, Wg, A1f, A2f);
  cbias_k<<<dim3(2), dim3(256), 0, stream>>>(bl, bh, Wg, bg, cb);
  transpose_w_k<<<dim3(16, 16), dim3(256), 0, stream>>>(Wl, W4t, 512, 512);
  transpose_w_k<<<dim3(16, 16), dim3(256), 0, stream>>>(Wh, W4t + 512 * 512, 512, 512);
  transpose_w_k<<<dim3(16, 16), dim3(256), 0, stream>>>(A1f, W4t + 2 * 512 * 512, 512, 512);
  transpose_w_k<<<dim3(16, 16), dim3(256), 0, stream>>>(A2f, W4t + 3 * 512 * 512, 512, 512);
  mega_k<<<dim3(16, MROWS / 256), dim3(256), 0, stream>>>(x, W4t, uT, vT, p1T, p2T);
  tail_k<<<dim3(NBATCH), dim3(256), 0, stream>>>(uT, vT, p1T, p2T, FlB, bl, bh, cb, x, out);
  ln_inplace_k<<<dim3(MROWS), dim3(256), 0, stream>>>(out, gamma, beta);
}